// Round 3
// baseline (240.816 us; speedup 1.0000x reference)
//
#include <hip/hip_runtime.h>
#include <math.h>

// Problem: B=8, C=64, T=16, H=64, W=64, text_dim=768
// out[b,c,:,h,w] = D^T diag(w[b,c,:]) D @ r[b,c,:,h,w]
// w[b, c*16+k] = sigmoid(E_txt[b] . Wf[c*16+k] + bf[c*16+k])
//
// SINGLE fused kernel: each block (bc = blk>>2) computes its own 16 gate
// dots (redundant x4 across chunk-blocks; Wf=3MB is LLC-resident), builds
// M = D^T diag(w) D in LDS, then streams y = M @ x over its 4 chunks.

#define HW4 1024         // H*W/4 (float4 units)

typedef float f4 __attribute__((ext_vector_type(4)));

__global__ __launch_bounds__(256, 4) void fused_kernel(
    const float* __restrict__ r,     // (512, 16, 4096)
    const float* __restrict__ E,     // (8, 768)
    const float* __restrict__ Wf,    // (1024, 768)
    const float* __restrict__ bf,    // (1024,)
    float* __restrict__ out)
{
    __shared__ float Dl[16][16];
    __shared__ float wv[16];
    __shared__ __align__(16) float Ms[256];   // Ms[k*16+t] = M[t][k]

    const int tid   = threadIdx.x;
    const int wave  = tid >> 6;
    const int lane  = tid & 63;
    const int bc    = blockIdx.x >> 2;        // 0..511
    const int chunk = (blockIdx.x & 3) * 4 + wave;
    const int b     = bc >> 6;                // 0..7
    const int c     = bc & 63;                // 0..63
    const int krow  = tid >> 4;               // 0..15 (gate row / Dl row / M row)
    const int sub   = tid & 15;               // 0..15

    const size_t base = (size_t)bc * (16 * 4096);
    const f4* rp = (const f4*)(r + base);
    f4*       op = (f4*)(out + base);
    const int col = chunk * 64 + lane;

    // ---- gate partial: dot(E[b], Wf[c*16+krow]), this thread's 12 f4 ----
    // (issued FIRST so the gate's waitcnt doesn't drain the x prefetches)
    const f4* W4 = (const f4*)Wf + (size_t)(c * 16 + krow) * 192 + sub;
    const f4* E4 = (const f4*)E + b * 192 + sub;
    float p0 = 0.f, p1 = 0.f, p2 = 0.f, p3 = 0.f;
#pragma unroll
    for (int j = 0; j < 12; j += 4) {
        f4 w0 = W4[16*(j+0)], e0 = E4[16*(j+0)];
        f4 w1 = W4[16*(j+1)], e1 = E4[16*(j+1)];
        f4 w2 = W4[16*(j+2)], e2 = E4[16*(j+2)];
        f4 w3 = W4[16*(j+3)], e3 = E4[16*(j+3)];
        p0 = fmaf(w0.x,e0.x,p0); p0 = fmaf(w0.y,e0.y,p0);
        p0 = fmaf(w0.z,e0.z,p0); p0 = fmaf(w0.w,e0.w,p0);
        p1 = fmaf(w1.x,e1.x,p1); p1 = fmaf(w1.y,e1.y,p1);
        p1 = fmaf(w1.z,e1.z,p1); p1 = fmaf(w1.w,e1.w,p1);
        p2 = fmaf(w2.x,e2.x,p2); p2 = fmaf(w2.y,e2.y,p2);
        p2 = fmaf(w2.z,e2.z,p2); p2 = fmaf(w2.w,e2.w,p2);
        p3 = fmaf(w3.x,e3.x,p3); p3 = fmaf(w3.y,e3.y,p3);
        p3 = fmaf(w3.z,e3.z,p3); p3 = fmaf(w3.w,e3.w,p3);
    }

    // ---- issue the first 8 x-loads (latency hides under reduce+M build) ----
    f4 xb[8];
#pragma unroll
    for (int k = 0; k < 8; ++k)
        xb[k] = __builtin_nontemporal_load(&rp[k * HW4 + col]);

    // ---- finish gate: 16-lane reduce + sigmoid -> wv[krow] ----
    float p = (p0 + p1) + (p2 + p3);
    p += __shfl_xor(p, 1, 64);
    p += __shfl_xor(p, 2, 64);
    p += __shfl_xor(p, 4, 64);
    p += __shfl_xor(p, 8, 64);

    // DCT row constants (same arithmetic as before)
    Dl[krow][sub] = (krow == 0)
        ? 0.25f
        : cospif((sub + 0.5f) * (float)krow * (1.0f / 16.0f)) * 0.35355339059327373f;
    if (sub == 0) {
        float s = p + bf[c * 16 + krow];
        wv[krow] = 1.0f / (1.0f + expf(-s));
    }
    __syncthreads();

    // ---- M[i][j] = sum_k D[k][i]*w[k]*D[k][j], stored k-major ----
    {
        float s = 0.f;
#pragma unroll
        for (int k = 0; k < 16; ++k)
            s = fmaf(Dl[k][krow] * wv[k], Dl[k][sub], s);
        Ms[sub * 16 + krow] = s;   // Ms[k*16+t] == M[t][k]
    }
    __syncthreads();

    // ---- streaming transform, k-major (same accumulation order) ----
    f4 y[16];
#pragma unroll
    for (int t = 0; t < 16; ++t)
        y[t] = (f4){0.f, 0.f, 0.f, 0.f};

#pragma unroll
    for (int k = 0; k < 16; ++k) {
        f4 xk = xb[k & 7];
        if (k + 8 < 16)
            xb[k & 7] = __builtin_nontemporal_load(&rp[(k + 8) * HW4 + col]);
        const f4* Mk = (const f4*)(Ms + k * 16);
#pragma unroll
        for (int t4 = 0; t4 < 4; ++t4) {
            f4 m = Mk[t4];   // M[4t4+0..3][k], uniform ds_read_b128
            y[4 * t4 + 0].x = fmaf(m.x, xk.x, y[4 * t4 + 0].x);
            y[4 * t4 + 0].y = fmaf(m.x, xk.y, y[4 * t4 + 0].y);
            y[4 * t4 + 0].z = fmaf(m.x, xk.z, y[4 * t4 + 0].z);
            y[4 * t4 + 0].w = fmaf(m.x, xk.w, y[4 * t4 + 0].w);
            y[4 * t4 + 1].x = fmaf(m.y, xk.x, y[4 * t4 + 1].x);
            y[4 * t4 + 1].y = fmaf(m.y, xk.y, y[4 * t4 + 1].y);
            y[4 * t4 + 1].z = fmaf(m.y, xk.z, y[4 * t4 + 1].z);
            y[4 * t4 + 1].w = fmaf(m.y, xk.w, y[4 * t4 + 1].w);
            y[4 * t4 + 2].x = fmaf(m.z, xk.x, y[4 * t4 + 2].x);
            y[4 * t4 + 2].y = fmaf(m.z, xk.y, y[4 * t4 + 2].y);
            y[4 * t4 + 2].z = fmaf(m.z, xk.z, y[4 * t4 + 2].z);
            y[4 * t4 + 2].w = fmaf(m.z, xk.w, y[4 * t4 + 2].w);
            y[4 * t4 + 3].x = fmaf(m.w, xk.x, y[4 * t4 + 3].x);
            y[4 * t4 + 3].y = fmaf(m.w, xk.y, y[4 * t4 + 3].y);
            y[4 * t4 + 3].z = fmaf(m.w, xk.z, y[4 * t4 + 3].z);
            y[4 * t4 + 3].w = fmaf(m.w, xk.w, y[4 * t4 + 3].w);
        }
    }

#pragma unroll
    for (int t = 0; t < 16; ++t)
        __builtin_nontemporal_store(y[t], &op[t * HW4 + col]);
}

extern "C" void kernel_launch(void* const* d_in, const int* in_sizes, int n_in,
                              void* d_out, int out_size, void* d_ws, size_t ws_size,
                              hipStream_t stream) {
    const float* r  = (const float*)d_in[0];   // 33554432
    const float* E  = (const float*)d_in[1];   // 6144
    const float* Wf = (const float*)d_in[2];   // 786432
    const float* bf = (const float*)d_in[3];   // 1024
    float* out = (float*)d_out;

    fused_kernel<<<2048, 256, 0, stream>>>(r, E, Wf, bf, out);
}